// Round 1
// baseline (1175.530 us; speedup 1.0000x reference)
//
#include <hip/hip_runtime.h>
#include <cstddef>

// Shapes: B=8, CIN=128, N=2048, K=16, G=4, COUT=256, L=192, CL=48, NL=64, CNL=16
constexpr int NN  = 2048;
constexpr int GG  = 4;

// ---------------------------------------------------------------------------
// Kernel A: local branch. One block per (b,n). 192 threads = one output channel
// each. Computes pe-MLP, lk, lv, att softmax, local_feature; scatters att into
// cent via atomicAdd.
// ---------------------------------------------------------------------------
__global__ __launch_bounds__(192) void local_kernel(
    const float* __restrict__ x, const float* __restrict__ abs_x,
    const float* __restrict__ points,
    const float* __restrict__ Wq, const float* __restrict__ Wk, const float* __restrict__ Wv,
    const float* __restrict__ pe_w1, const float* __restrict__ pe_b1,
    const float* __restrict__ pe_w2, const float* __restrict__ pe_b2,
    const int* __restrict__ idx,
    float* __restrict__ out, float* __restrict__ cent)
{
    const int bn  = blockIdx.x;
    const int b   = bn >> 11;
    const int n   = bn & 2047;
    const int tid = threadIdx.x;

    __shared__ __align__(16) float sx[128][16];   // x[b,:,n,:]
    __shared__ __align__(16) float sh[16][192];   // h[kk][d]
    __shared__ float slk[192][17];                // lk (+pe), padded
    __shared__ float slq[192];
    __shared__ float sabs[64];
    __shared__ float spts[3][16];
    __shared__ int   sidx[16];
    __shared__ float satt[4][16];

    if (tid < 16) sidx[tid] = idx[(bn << 4) + tid];
    {   // x tile: address = ((b*128+c)*2048+n)*16+kk
        const float* xb = x + ((size_t)b * 128 * NN + n) * 16;
        for (int i = tid; i < 128 * 16; i += 192) {
            int c = i >> 4, kk = i & 15;
            sx[c][kk] = xb[(size_t)c * (NN * 16) + kk];
        }
    }
    if (tid < 64) sabs[tid] = abs_x[((size_t)b * 64 + tid) * NN + n];
    __syncthreads();
    if (tid < 48) {
        int c = tid >> 4, kk = tid & 15;
        spts[c][kk] = points[((size_t)b * 3 + c) * NN + sidx[kk]];
    }
    __syncthreads();

    // h = relu(rel^T @ pe_w1 + pe_b1): thread d computes sh[:, d]
    {
        const int d = tid;
        const float w0 = pe_w1[d], w1 = pe_w1[192 + d], w2 = pe_w1[384 + d];
        const float b1 = pe_b1[d];
        const float p0 = spts[0][0], p1 = spts[1][0], p2 = spts[2][0];
        #pragma unroll
        for (int kk = 0; kk < 16; ++kk) {
            float r0 = spts[0][kk] - p0;
            float r1 = spts[1][kk] - p1;
            float r2 = spts[2][kk] - p2;
            float hv = fmaf(r0, w0, fmaf(r1, w1, fmaf(r2, w2, b1)));
            sh[kk][d] = fmaxf(hv, 0.f);
        }
    }
    __syncthreads();

    const int o = tid;            // output channel 0..191
    float acc[16];                // pe, then lk accumulator
    float lv[16];
    {
        const float b2 = pe_b2[o];
        #pragma unroll
        for (int kk = 0; kk < 16; ++kk) { acc[kk] = b2; lv[kk] = 0.f; }
    }
    // pe[kk][o] = sum_d h[kk][d] * pe_w2[d][o]
    for (int d0 = 0; d0 < 192; d0 += 4) {
        const float w20 = pe_w2[(d0 + 0) * 192 + o];
        const float w21 = pe_w2[(d0 + 1) * 192 + o];
        const float w22 = pe_w2[(d0 + 2) * 192 + o];
        const float w23 = pe_w2[(d0 + 3) * 192 + o];
        #pragma unroll
        for (int kk = 0; kk < 16; ++kk) {
            const float4 hv = *(const float4*)&sh[kk][d0];
            acc[kk] = fmaf(hv.x, w20, fmaf(hv.y, w21, fmaf(hv.z, w22, fmaf(hv.w, w23, acc[kk]))));
        }
    }
    // lq[o]
    float lqv = 0.f;
    #pragma unroll 8
    for (int c = 0; c < 64; ++c) lqv = fmaf(Wq[o * 64 + c], sabs[c], lqv);
    slq[o] = lqv;
    // lk[o][kk] += Wk[o][c]*(x[c]+x[c+64]);  lv[o][kk] = Wv[o][c]*x[c]
    for (int c = 0; c < 128; ++c) {
        const float wv = Wv[o * 128 + c];
        const float wk = Wk[o * 64 + (c & 63)];
        #pragma unroll
        for (int q = 0; q < 4; ++q) {
            const float4 xv = *(const float4*)&sx[c][q * 4];
            acc[q * 4 + 0] = fmaf(wk, xv.x, acc[q * 4 + 0]);
            acc[q * 4 + 1] = fmaf(wk, xv.y, acc[q * 4 + 1]);
            acc[q * 4 + 2] = fmaf(wk, xv.z, acc[q * 4 + 2]);
            acc[q * 4 + 3] = fmaf(wk, xv.w, acc[q * 4 + 3]);
            lv[q * 4 + 0]  = fmaf(wv, xv.x, lv[q * 4 + 0]);
            lv[q * 4 + 1]  = fmaf(wv, xv.y, lv[q * 4 + 1]);
            lv[q * 4 + 2]  = fmaf(wv, xv.z, lv[q * 4 + 2]);
            lv[q * 4 + 3]  = fmaf(wv, xv.w, lv[q * 4 + 3]);
        }
    }
    #pragma unroll
    for (int kk = 0; kk < 16; ++kk) slk[o][kk] = acc[kk];
    __syncthreads();

    // logits + softmax over k, per (g,kk) on wave 0
    if (tid < 64) {
        const int g = tid >> 4, kk = tid & 15;
        const int ob = g * 48;
        float lg = 0.f;
        #pragma unroll 8
        for (int c = 0; c < 48; ++c) lg = fmaf(slq[ob + c], slk[ob + c][kk], lg);
        float m = lg;
        #pragma unroll
        for (int off = 1; off < 16; off <<= 1) m = fmaxf(m, __shfl_xor(m, off, 16));
        const float e = __expf(lg - m);
        float s = e;
        #pragma unroll
        for (int off = 1; off < 16; off <<= 1) s += __shfl_xor(s, off, 16);
        const float a = e / s;
        satt[g][kk] = a;
        atomicAdd(&cent[((size_t)(b * GG + g) << 11) + sidx[kk]], a);
    }
    __syncthreads();

    {
        const int g = o / 48;
        float fo = 0.f;
        #pragma unroll
        for (int kk = 0; kk < 16; ++kk) fo = fmaf(satt[g][kk], lv[kk], fo);
        out[(((size_t)b << 8) + o) * NN + n] = fo;
    }
}

// ---------------------------------------------------------------------------
// Kernel C: per (b,g): top-16 of cent row (tie-break: lower index, matching
// jax.lax.top_k), then nonlocal prep: nkpe = nk_sel + pe_nl, nv2j, tanh(vals).
// ---------------------------------------------------------------------------
__global__ __launch_bounds__(256) void topk_prep_kernel(
    const float* __restrict__ abs_x, const float* __restrict__ points,
    const float* __restrict__ Wnk, const float* __restrict__ Wnv2,
    const float* __restrict__ npe_w1, const float* __restrict__ npe_b1,
    const float* __restrict__ npe_w2, const float* __restrict__ npe_b2,
    const float* __restrict__ cent,
    float* __restrict__ nkpe, float* __restrict__ nv2j, float* __restrict__ tanhv)
{
    const int bg  = blockIdx.x;     // b*4+g
    const int b   = bg >> 2, g = bg & 3;
    const int tid = threadIdx.x;
    __shared__ float sc[2048];
    __shared__ float rv[4];  __shared__ int ri[4];
    __shared__ float svals[16]; __shared__ int sinds[16];
    __shared__ float srel[3][16];
    __shared__ float sh2[16][16];

    for (int i = tid; i < 2048; i += 256) sc[i] = cent[((size_t)bg << 11) + i];
    __syncthreads();
    for (int t = 0; t < 16; ++t) {
        float bv = -1e30f; int bi = 1 << 30;
        for (int i = tid; i < 2048; i += 256) {      // ascending -> keeps lowest idx on ties
            float v = sc[i];
            if (v > bv) { bv = v; bi = i; }
        }
        #pragma unroll
        for (int off = 1; off < 64; off <<= 1) {
            float ov = __shfl_xor(bv, off, 64);
            int   oi = __shfl_xor(bi, off, 64);
            if (ov > bv || (ov == bv && oi < bi)) { bv = ov; bi = oi; }
        }
        if ((tid & 63) == 0) { rv[tid >> 6] = bv; ri[tid >> 6] = bi; }
        __syncthreads();
        if (tid == 0) {
            for (int w = 1; w < 4; ++w)
                if (rv[w] > bv || (rv[w] == bv && ri[w] < bi)) { bv = rv[w]; bi = ri[w]; }
            svals[t] = bv; sinds[t] = bi;
            sc[bi] = -1e30f;
        }
        __syncthreads();
    }

    if (tid < 48) {
        int c = tid >> 4, j = tid & 15;
        srel[c][j] = points[((size_t)b * 3 + c) * NN + sinds[j]]
                   - points[((size_t)b * 3 + c) * NN + sinds[0]];
    }
    __syncthreads();
    {   // h2[j][d] = relu(rel_nl^T @ npe_w1 + npe_b1)
        int j = tid >> 4, d = tid & 15;
        float a = npe_b1[g * 16 + d];
        #pragma unroll
        for (int c = 0; c < 3; ++c) a = fmaf(srel[c][j], npe_w1[((g * 3 + c) << 4) + d], a);
        sh2[j][d] = fmaxf(a, 0.f);
    }
    __syncthreads();
    {   // pe_nl[c][j] + nk_sel[c][j];  nv2j[c][j]
        int c = tid >> 4, j = tid & 15;
        float a = npe_b2[g * 16 + c];
        #pragma unroll
        for (int d = 0; d < 16; ++d) a = fmaf(sh2[j][d], npe_w2[((g * 16 + d) << 4) + c], a);
        float nk = 0.f, nv = 0.f;
        const int col = sinds[j];
        const float* a2  = abs_x + (size_t)b * 64 * NN + col;
        const float* wkr = Wnk  + ((size_t)(g * 16 + c) << 6);
        const float* wvr = Wnv2 + ((size_t)(g * 16 + c) << 6);
        for (int ci = 0; ci < 64; ++ci) {
            float av = a2[(size_t)ci * NN];
            nk = fmaf(wkr[ci], av, nk);
            nv = fmaf(wvr[ci], av, nv);
        }
        nkpe[((size_t)bg << 8) + (c << 4) + j] = nk + a;
        nv2j[((size_t)bg << 8) + (c << 4) + j] = nv;
    }
    if (tid < 16) tanhv[(bg << 4) + tid] = tanhf(svals[tid]);
}

// ---------------------------------------------------------------------------
// Kernel D: nonlocal branch per n. Block = (b, 64 n's); thread = (g, n_local).
// ---------------------------------------------------------------------------
__global__ __launch_bounds__(256) void nonlocal_kernel(
    const float* __restrict__ abs_x,
    const float* __restrict__ Wnq, const float* __restrict__ Wnv1, const float* __restrict__ Wnv2,
    const float* __restrict__ nkpe, const float* __restrict__ nv2j, const float* __restrict__ tanhv,
    float* __restrict__ out)
{
    const int blk = blockIdx.x;
    const int b   = blk >> 5;
    const int n0  = (blk & 31) << 6;
    const int tid = threadIdx.x;
    const int nl  = tid & 63;
    const int g   = tid >> 6;

    __shared__ float sa2[64][64];
    __shared__ float snkpe[4][16][16];
    __shared__ float snv2j[4][16][16];
    __shared__ float stanh[4][16];

    for (int i = tid; i < 64 * 64; i += 256) {
        int ci = i >> 6, c2 = i & 63;
        sa2[ci][c2] = abs_x[((size_t)b * 64 + ci) * NN + n0 + c2];
    }
    for (int i = tid; i < 1024; i += 256) {
        ((float*)snkpe)[i] = nkpe[((size_t)b << 10) + i];
        ((float*)snv2j)[i] = nv2j[((size_t)b << 10) + i];
    }
    if (tid < 64) ((float*)stanh)[tid] = tanhv[(b << 6) + tid];
    __syncthreads();

    float nq[16], nv1[16], nv2[16];
    #pragma unroll
    for (int c = 0; c < 16; ++c) { nq[c] = 0.f; nv1[c] = 0.f; nv2[c] = 0.f; }
    const float* wq  = Wnq  + (size_t)(g << 4) * 64;
    const float* wv1 = Wnv1 + (size_t)(g << 4) * 64;
    const float* wv2 = Wnv2 + (size_t)(g << 4) * 64;
    for (int ci = 0; ci < 64; ++ci) {
        const float a = sa2[ci][nl];
        #pragma unroll
        for (int c = 0; c < 16; ++c) {
            nq[c]  = fmaf(wq [(c << 6) + ci], a, nq[c]);
            nv1[c] = fmaf(wv1[(c << 6) + ci], a, nv1[c]);
            nv2[c] = fmaf(wv2[(c << 6) + ci], a, nv2[c]);
        }
    }

    float lg[16];
    #pragma unroll
    for (int j = 0; j < 16; ++j) {
        float a = 0.f;
        #pragma unroll
        for (int c = 0; c < 16; ++c) a = fmaf(nq[c], snkpe[g][c][j], a);
        lg[j] = a;
    }
    float m = lg[0];
    #pragma unroll
    for (int j = 1; j < 16; ++j) m = fmaxf(m, lg[j]);
    float s = 0.f;
    float w[16];
    #pragma unroll
    for (int j = 0; j < 16; ++j) { w[j] = __expf(lg[j] - m); s += w[j]; }
    const float inv = 1.f / s;
    float ws = 0.f;
    #pragma unroll
    for (int j = 0; j < 16; ++j) { w[j] = w[j] * inv * stanh[g][j]; ws += w[j]; }
    #pragma unroll
    for (int c = 0; c < 16; ++c) {
        float v = (nv1[c] - nv2[c]) * ws;
        #pragma unroll
        for (int j = 0; j < 16; ++j) v = fmaf(w[j], snv2j[g][c][j], v);
        out[(((size_t)b << 8) + 192 + (g << 4) + c) * NN + n0 + nl] = v;
    }
}

// ---------------------------------------------------------------------------
extern "C" void kernel_launch(void* const* d_in, const int* in_sizes, int n_in,
                              void* d_out, int out_size, void* d_ws, size_t ws_size,
                              hipStream_t stream)
{
    (void)in_sizes; (void)n_in; (void)out_size; (void)ws_size;
    const float* x      = (const float*)d_in[0];
    const float* abs_x  = (const float*)d_in[1];
    const float* points = (const float*)d_in[2];
    const float* Wq     = (const float*)d_in[3];
    const float* Wk     = (const float*)d_in[4];
    const float* Wv     = (const float*)d_in[5];
    const float* Wnq    = (const float*)d_in[6];
    const float* Wnk    = (const float*)d_in[7];
    const float* Wnv1   = (const float*)d_in[8];
    const float* Wnv2   = (const float*)d_in[9];
    const float* pe_w1  = (const float*)d_in[10];
    const float* pe_b1  = (const float*)d_in[11];
    const float* pe_w2  = (const float*)d_in[12];
    const float* pe_b2  = (const float*)d_in[13];
    const float* npe_w1 = (const float*)d_in[14];
    const float* npe_b1 = (const float*)d_in[15];
    const float* npe_w2 = (const float*)d_in[16];
    const float* npe_b2 = (const float*)d_in[17];
    const int*   idx    = (const int*)d_in[18];
    float* out = (float*)d_out;

    // workspace layout (floats): cent[8*4*2048] | nkpe[8192] | nv2j[8192] | tanhv[512]
    float* cent  = (float*)d_ws;
    float* nkpeW = cent + 8 * 4 * 2048;
    float* nv2jW = nkpeW + 8192;
    float* tanhW = nv2jW + 8192;

    hipMemsetAsync(cent, 0, (size_t)8 * 4 * 2048 * sizeof(float), stream);
    local_kernel<<<8 * 2048, 192, 0, stream>>>(x, abs_x, points, Wq, Wk, Wv,
                                               pe_w1, pe_b1, pe_w2, pe_b2, idx, out, cent);
    topk_prep_kernel<<<32, 256, 0, stream>>>(abs_x, points, Wnk, Wnv2,
                                             npe_w1, npe_b1, npe_w2, npe_b2,
                                             cent, nkpeW, nv2jW, tanhW);
    nonlocal_kernel<<<8 * 32, 256, 0, stream>>>(abs_x, Wnq, Wnv1, Wnv2,
                                                nkpeW, nv2jW, tanhW, out);
}

// Round 3
// 307.599 us; speedup vs baseline: 3.8216x; 3.8216x over previous
//
#include <hip/hip_runtime.h>
#include <cstddef>

// Shapes: B=8, CIN=128, N=2048, K=16, G=4, COUT=256, L=192, CL=48, NL=64, CNL=16
constexpr int NN = 2048;
constexpr int GG = 4;

__device__ __forceinline__ short f2bf(float f) {
    unsigned int u = __float_as_uint(f);
    unsigned int r = (u + 0x7FFFu + ((u >> 16) & 1u)) >> 16;
    return (short)r;
}
__device__ __forceinline__ float bf2f(short s) {
    return __uint_as_float(((unsigned int)(unsigned short)s) << 16);
}

// ---------------------------------------------------------------------------
// prep_q: Qbuf[g][c2][row] f32 (row<64: M_g[row][c2] = sum_o Wk[o][row]Wq[o][c2];
// row>=64: W2q_g[row-64][c2] = sum_o pe_w2[row-64][o]Wq[o][c2]), o in group g.
// ---------------------------------------------------------------------------
__global__ __launch_bounds__(256) void prep_q(const float* __restrict__ Wq,
                                              const float* __restrict__ Wk,
                                              const float* __restrict__ pe_w2,
                                              float* __restrict__ Qbuf) {
    const int g = blockIdx.x >> 6, c2 = blockIdx.x & 63;
    const int row = threadIdx.x;
    float acc = 0.f;
    if (row < 64) {
        for (int j = 0; j < 48; ++j) {
            const int o = g * 48 + j;
            acc = fmaf(Wk[o * 64 + row], Wq[o * 64 + c2], acc);
        }
    } else {
        const int d = row - 64;
        for (int j = 0; j < 48; ++j) {
            const int o = g * 48 + j;
            acc = fmaf(pe_w2[(size_t)d * 192 + o], Wq[o * 64 + c2], acc);
        }
    }
    Qbuf[((size_t)(g * 64 + c2) << 8) + row] = acc;
}

// ---------------------------------------------------------------------------
// local_v3: fused local branch, all-f32 logits (top-k safe). Block = (b, 8 n).
// ---------------------------------------------------------------------------
__global__ __launch_bounds__(256) void local_v3(
    const float* __restrict__ x, const float* __restrict__ abs_x,
    const float* __restrict__ points, const float* __restrict__ Wv,
    const float* __restrict__ pe_w1, const float* __restrict__ pe_b1,
    const int* __restrict__ idx, const float* __restrict__ Qbuf,
    float* __restrict__ out, float* __restrict__ cent)
{
    const int bn = blockIdx.x;
    const int b  = bn >> 8;
    const int n0 = (bn & 255) << 3;
    const int tid = threadIdx.x;

    __shared__ __align__(16) float sxsum[64][132];   // x_lo+x_hi, f32 (logitA)
    __shared__ __align__(16) short sxbf[128][132];   // x bf16 (xw path only)
    __shared__ __align__(16) float sa2[64][8];
    __shared__ float sq[4][8][65];                   // q~ per (g,nl)
    __shared__ float sw[4][8][193];                  // w~ per (g,nl)
    __shared__ float spart[128][2][4];               // h-contraction partials
    __shared__ float slog[4][128];
    __shared__ float satt[4][128];
    __shared__ float sxw[4][128][8];
    __shared__ float spts[3][8][16];
    __shared__ int   sidx[128];

    // ---- stage0: idx, a2, x (f32 sum + bf16 copy) ----
    if (tid < 128) sidx[tid] = idx[((size_t)b * NN + n0) * 16 + tid];
    for (int i = tid; i < 512; i += 256) {
        int c = i >> 3, nl = i & 7;
        sa2[c][nl] = abs_x[((size_t)b * 64 + c) * NN + n0 + nl];
    }
    {
        const float* xb = x + ((size_t)b * 128) * NN * 16 + (size_t)n0 * 16;
        for (int i = tid; i < 2048; i += 256) {
            int c = i >> 5, col = (i & 31) * 4;
            float4 vlo = *(const float4*)(xb + (size_t)c * (NN * 16) + col);
            float4 vhi = *(const float4*)(xb + (size_t)(c + 64) * (NN * 16) + col);
            *(float4*)&sxsum[c][col] = make_float4(vlo.x + vhi.x, vlo.y + vhi.y,
                                                   vlo.z + vhi.z, vlo.w + vhi.w);
            unsigned p0 = (unsigned)(unsigned short)f2bf(vlo.x) | ((unsigned)(unsigned short)f2bf(vlo.y) << 16);
            unsigned p1 = (unsigned)(unsigned short)f2bf(vlo.z) | ((unsigned)(unsigned short)f2bf(vlo.w) << 16);
            *(unsigned*)&sxbf[c][col]     = p0;
            *(unsigned*)&sxbf[c][col + 2] = p1;
            unsigned q0 = (unsigned)(unsigned short)f2bf(vhi.x) | ((unsigned)(unsigned short)f2bf(vhi.y) << 16);
            unsigned q1 = (unsigned)(unsigned short)f2bf(vhi.z) | ((unsigned)(unsigned short)f2bf(vhi.w) << 16);
            *(unsigned*)&sxbf[c + 64][col]     = q0;
            *(unsigned*)&sxbf[c + 64][col + 2] = q1;
        }
    }
    __syncthreads();

    // ---- spts gather (needs sidx) ----
    for (int i = tid; i < 384; i += 256) {
        int c = i >> 7, r = i & 127;
        spts[c][r >> 4][r & 15] = points[((size_t)b * 3 + c) * NN + sidx[r]];
    }
    // ---- Q-stage: [q~; w~](g, row=tid) = Qbuf_g @ a2, all 8 n at once ----
    for (int g = 0; g < 4; ++g) {
        const float* qb = Qbuf + ((size_t)g << 14) + tid;  // (g*64+c2)*256 + row
        float acc[8] = {0.f, 0.f, 0.f, 0.f, 0.f, 0.f, 0.f, 0.f};
        for (int c2 = 0; c2 < 64; ++c2) {
            const float qv = qb[c2 << 8];
            const float4 a0 = *(const float4*)&sa2[c2][0];
            const float4 a1 = *(const float4*)&sa2[c2][4];
            acc[0] = fmaf(qv, a0.x, acc[0]); acc[1] = fmaf(qv, a0.y, acc[1]);
            acc[2] = fmaf(qv, a0.z, acc[2]); acc[3] = fmaf(qv, a0.w, acc[3]);
            acc[4] = fmaf(qv, a1.x, acc[4]); acc[5] = fmaf(qv, a1.y, acc[5]);
            acc[6] = fmaf(qv, a1.z, acc[6]); acc[7] = fmaf(qv, a1.w, acc[7]);
        }
        if (tid < 64) {
            #pragma unroll
            for (int nl = 0; nl < 8; ++nl) sq[g][nl][tid] = acc[nl];
        } else {
            #pragma unroll
            for (int nl = 0; nl < 8; ++nl) sw[g][nl][tid - 64] = acc[nl];
        }
    }
    __syncthreads();

    // ---- h-partials: spart[col][half][g] = sum_{d in half} h[col][d]*w~[g][nl][d] ----
    {
        const int col = tid & 127, half = tid >> 7;
        const int nl = col >> 4, kk = col & 15;
        const float r0 = spts[0][nl][kk] - spts[0][nl][0];
        const float r1 = spts[1][nl][kk] - spts[1][nl][0];
        const float r2 = spts[2][nl][kk] - spts[2][nl][0];
        float pB0 = 0.f, pB1 = 0.f, pB2 = 0.f, pB3 = 0.f;
        const int d0 = half * 96;
        for (int d = d0; d < d0 + 96; ++d) {
            float h = fmaf(r0, pe_w1[d], fmaf(r1, pe_w1[192 + d], fmaf(r2, pe_w1[384 + d], pe_b1[d])));
            h = fmaxf(h, 0.f);
            pB0 = fmaf(h, sw[0][nl][d], pB0);
            pB1 = fmaf(h, sw[1][nl][d], pB1);
            pB2 = fmaf(h, sw[2][nl][d], pB2);
            pB3 = fmaf(h, sw[3][nl][d], pB3);
        }
        spart[col][half][0] = pB0; spart[col][half][1] = pB1;
        spart[col][half][2] = pB2; spart[col][half][3] = pB3;
    }
    __syncthreads();

    // ---- logits: slog[g][col] = q~ . xsum[:,col] + h-part ----
    #pragma unroll
    for (int rep = 0; rep < 2; ++rep) {
        const int e = rep * 256 + tid;
        const int g = e >> 7, col = e & 127, nl = col >> 4;
        float acc = spart[col][0][g] + spart[col][1][g];
        for (int c = 0; c < 64; ++c)
            acc = fmaf(sq[g][nl][c], sxsum[c][col], acc);
        slog[g][col] = acc;
    }
    __syncthreads();

    // ---- softmax over kk per (g,nl); scatter att into cent ----
    if (tid < 32) {
        const int g = tid >> 3, nl = tid & 7;
        float lg[16], m = -1e30f;
        #pragma unroll
        for (int kk = 0; kk < 16; ++kk) { lg[kk] = slog[g][nl * 16 + kk]; m = fmaxf(m, lg[kk]); }
        float s = 0.f;
        #pragma unroll
        for (int kk = 0; kk < 16; ++kk) { lg[kk] = __expf(lg[kk] - m); s += lg[kk]; }
        const float inv = 1.f / s;
        #pragma unroll
        for (int kk = 0; kk < 16; ++kk) {
            const float a = lg[kk] * inv;
            satt[g][nl * 16 + kk] = a;
            atomicAdd(&cent[((size_t)(b * GG + g) << 11) + sidx[nl * 16 + kk]], a);
        }
    }
    __syncthreads();

    // ---- xw[g][c][nl] = sum_kk x[c][col]*att[g][col] ----
    {
        const int c = tid & 127, h2 = tid >> 7;
        #pragma unroll
        for (int t = 0; t < 4; ++t) {
            const int nl = h2 + t * 2;
            float xv[16];
            #pragma unroll
            for (int kk = 0; kk < 16; ++kk) xv[kk] = bf2f(sxbf[c][nl * 16 + kk]);
            #pragma unroll
            for (int g = 0; g < 4; ++g) {
                float v = 0.f;
                #pragma unroll
                for (int kk = 0; kk < 16; ++kk) v = fmaf(xv[kk], satt[g][nl * 16 + kk], v);
                sxw[g][c][nl] = v;
            }
        }
    }
    __syncthreads();

    // ---- out[o][n] = Wv[o,:] . xw[g(o)][:,n] ----
    for (int i = tid; i < 1536; i += 256) {
        const int o = i >> 3, nl = i & 7;
        const int g = o / 48;
        const float* wv = Wv + (size_t)o * 128;
        float a = 0.f;
        for (int c = 0; c < 128; c += 4) {
            const float4 w4 = *(const float4*)(wv + c);
            a = fmaf(w4.x, sxw[g][c + 0][nl], a);
            a = fmaf(w4.y, sxw[g][c + 1][nl], a);
            a = fmaf(w4.z, sxw[g][c + 2][nl], a);
            a = fmaf(w4.w, sxw[g][c + 3][nl], a);
        }
        out[(((size_t)b << 8) + o) * NN + n0 + nl] = a;
    }
}

// ---------------------------------------------------------------------------
// Kernel C: per (b,g): top-16 of cent row, then nonlocal prep (unchanged).
// ---------------------------------------------------------------------------
__global__ __launch_bounds__(256) void topk_prep_kernel(
    const float* __restrict__ abs_x, const float* __restrict__ points,
    const float* __restrict__ Wnk, const float* __restrict__ Wnv2,
    const float* __restrict__ npe_w1, const float* __restrict__ npe_b1,
    const float* __restrict__ npe_w2, const float* __restrict__ npe_b2,
    const float* __restrict__ cent,
    float* __restrict__ nkpe, float* __restrict__ nv2j, float* __restrict__ tanhv)
{
    const int bg  = blockIdx.x;
    const int b   = bg >> 2, g = bg & 3;
    const int tid = threadIdx.x;
    __shared__ float sc[2048];
    __shared__ float rv[4];  __shared__ int ri[4];
    __shared__ float svals[16]; __shared__ int sinds[16];
    __shared__ float srel[3][16];
    __shared__ float sh2[16][16];

    for (int i = tid; i < 2048; i += 256) sc[i] = cent[((size_t)bg << 11) + i];
    __syncthreads();
    for (int t = 0; t < 16; ++t) {
        float bv = -1e30f; int bi = 1 << 30;
        for (int i = tid; i < 2048; i += 256) {
            float v = sc[i];
            if (v > bv) { bv = v; bi = i; }
        }
        #pragma unroll
        for (int off = 1; off < 64; off <<= 1) {
            float ov = __shfl_xor(bv, off, 64);
            int   oi = __shfl_xor(bi, off, 64);
            if (ov > bv || (ov == bv && oi < bi)) { bv = ov; bi = oi; }
        }
        if ((tid & 63) == 0) { rv[tid >> 6] = bv; ri[tid >> 6] = bi; }
        __syncthreads();
        if (tid == 0) {
            for (int w = 1; w < 4; ++w)
                if (rv[w] > bv || (rv[w] == bv && ri[w] < bi)) { bv = rv[w]; bi = ri[w]; }
            svals[t] = bv; sinds[t] = bi;
            sc[bi] = -1e30f;
        }
        __syncthreads();
    }

    if (tid < 48) {
        int c = tid >> 4, j = tid & 15;
        srel[c][j] = points[((size_t)b * 3 + c) * NN + sinds[j]]
                   - points[((size_t)b * 3 + c) * NN + sinds[0]];
    }
    __syncthreads();
    {
        int j = tid >> 4, d = tid & 15;
        float a = npe_b1[g * 16 + d];
        #pragma unroll
        for (int c = 0; c < 3; ++c) a = fmaf(srel[c][j], npe_w1[((g * 3 + c) << 4) + d], a);
        sh2[j][d] = fmaxf(a, 0.f);
    }
    __syncthreads();
    {
        int c = tid >> 4, j = tid & 15;
        float a = npe_b2[g * 16 + c];
        #pragma unroll
        for (int d = 0; d < 16; ++d) a = fmaf(sh2[j][d], npe_w2[((g * 16 + d) << 4) + c], a);
        float nk = 0.f, nv = 0.f;
        const int col = sinds[j];
        const float* a2  = abs_x + (size_t)b * 64 * NN + col;
        const float* wkr = Wnk  + ((size_t)(g * 16 + c) << 6);
        const float* wvr = Wnv2 + ((size_t)(g * 16 + c) << 6);
        for (int ci = 0; ci < 64; ++ci) {
            float av = a2[(size_t)ci * NN];
            nk = fmaf(wkr[ci], av, nk);
            nv = fmaf(wvr[ci], av, nv);
        }
        nkpe[((size_t)bg << 8) + (c << 4) + j] = nk + a;
        nv2j[((size_t)bg << 8) + (c << 4) + j] = nv;
    }
    if (tid < 16) tanhv[(bg << 4) + tid] = tanhf(svals[tid]);
}

// ---------------------------------------------------------------------------
// Kernel D: nonlocal branch (unchanged).
// ---------------------------------------------------------------------------
__global__ __launch_bounds__(256) void nonlocal_kernel(
    const float* __restrict__ abs_x,
    const float* __restrict__ Wnq, const float* __restrict__ Wnv1, const float* __restrict__ Wnv2,
    const float* __restrict__ nkpe, const float* __restrict__ nv2j, const float* __restrict__ tanhv,
    float* __restrict__ out)
{
    const int blk = blockIdx.x;
    const int b   = blk >> 5;
    const int n0  = (blk & 31) << 6;
    const int tid = threadIdx.x;
    const int nl  = tid & 63;
    const int g   = tid >> 6;

    __shared__ float sa2[64][64];
    __shared__ float snkpe[4][16][16];
    __shared__ float snv2j[4][16][16];
    __shared__ float stanh[4][16];

    for (int i = tid; i < 64 * 64; i += 256) {
        int ci = i >> 6, c2 = i & 63;
        sa2[ci][c2] = abs_x[((size_t)b * 64 + ci) * NN + n0 + c2];
    }
    for (int i = tid; i < 1024; i += 256) {
        ((float*)snkpe)[i] = nkpe[((size_t)b << 10) + i];
        ((float*)snv2j)[i] = nv2j[((size_t)b << 10) + i];
    }
    if (tid < 64) ((float*)stanh)[tid] = tanhv[(b << 6) + tid];
    __syncthreads();

    float nq[16], nv1[16], nv2[16];
    #pragma unroll
    for (int c = 0; c < 16; ++c) { nq[c] = 0.f; nv1[c] = 0.f; nv2[c] = 0.f; }
    const float* wq  = Wnq  + (size_t)(g << 4) * 64;
    const float* wv1 = Wnv1 + (size_t)(g << 4) * 64;
    const float* wv2 = Wnv2 + (size_t)(g << 4) * 64;
    for (int ci = 0; ci < 64; ++ci) {
        const float a = sa2[ci][nl];
        #pragma unroll
        for (int c = 0; c < 16; ++c) {
            nq[c]  = fmaf(wq [(c << 6) + ci], a, nq[c]);
            nv1[c] = fmaf(wv1[(c << 6) + ci], a, nv1[c]);
            nv2[c] = fmaf(wv2[(c << 6) + ci], a, nv2[c]);
        }
    }

    float lg[16];
    #pragma unroll
    for (int j = 0; j < 16; ++j) {
        float a = 0.f;
        #pragma unroll
        for (int c = 0; c < 16; ++c) a = fmaf(nq[c], snkpe[g][c][j], a);
        lg[j] = a;
    }
    float m = lg[0];
    #pragma unroll
    for (int j = 1; j < 16; ++j) m = fmaxf(m, lg[j]);
    float s = 0.f;
    float w[16];
    #pragma unroll
    for (int j = 0; j < 16; ++j) { w[j] = __expf(lg[j] - m); s += w[j]; }
    const float inv = 1.f / s;
    float ws = 0.f;
    #pragma unroll
    for (int j = 0; j < 16; ++j) { w[j] = w[j] * inv * stanh[g][j]; ws += w[j]; }
    #pragma unroll
    for (int c = 0; c < 16; ++c) {
        float v = (nv1[c] - nv2[c]) * ws;
        #pragma unroll
        for (int j = 0; j < 16; ++j) v = fmaf(w[j], snv2j[g][c][j], v);
        out[(((size_t)b << 8) + 192 + (g << 4) + c) * NN + n0 + nl] = v;
    }
}

// ---------------------------------------------------------------------------
extern "C" void kernel_launch(void* const* d_in, const int* in_sizes, int n_in,
                              void* d_out, int out_size, void* d_ws, size_t ws_size,
                              hipStream_t stream)
{
    (void)in_sizes; (void)n_in; (void)out_size; (void)ws_size;
    const float* x      = (const float*)d_in[0];
    const float* abs_x  = (const float*)d_in[1];
    const float* points = (const float*)d_in[2];
    const float* Wq     = (const float*)d_in[3];
    const float* Wk     = (const float*)d_in[4];
    const float* Wv     = (const float*)d_in[5];
    const float* Wnq    = (const float*)d_in[6];
    const float* Wnk    = (const float*)d_in[7];
    const float* Wnv1   = (const float*)d_in[8];
    const float* Wnv2   = (const float*)d_in[9];
    const float* pe_w1  = (const float*)d_in[10];
    const float* pe_b1  = (const float*)d_in[11];
    const float* pe_w2  = (const float*)d_in[12];
    // pe_b2 (d_in[13]): constant logit shift per (g,n) -> cancels in softmax
    const float* npe_w1 = (const float*)d_in[14];
    const float* npe_b1 = (const float*)d_in[15];
    const float* npe_w2 = (const float*)d_in[16];
    const float* npe_b2 = (const float*)d_in[17];
    const int*   idx    = (const int*)d_in[18];
    float* out = (float*)d_out;

    // ws layout (floats): cent[65536] | Qbuf[65536] | nkpe[8192] | nv2j[8192] | tanh[512]
    float* cent  = (float*)d_ws;
    float* Qbuf  = cent + 65536;
    float* nkpeW = Qbuf + 65536;
    float* nv2jW = nkpeW + 8192;
    float* tanhW = nv2jW + 8192;

    hipMemsetAsync(cent, 0, (size_t)65536 * sizeof(float), stream);
    prep_q<<<256, 256, 0, stream>>>(Wq, Wk, pe_w2, Qbuf);
    local_v3<<<2048, 256, 0, stream>>>(x, abs_x, points, Wv, pe_w1, pe_b1,
                                       idx, Qbuf, out, cent);
    topk_prep_kernel<<<32, 256, 0, stream>>>(abs_x, points, Wnk, Wnv2,
                                             npe_w1, npe_b1, npe_w2, npe_b2,
                                             cent, nkpeW, nv2jW, tanhW);
    nonlocal_kernel<<<8 * 32, 256, 0, stream>>>(abs_x, Wnq, Wnv1, Wnv2,
                                                nkpeW, nv2jW, tanhW, out);
}

// Round 4
// 235.017 us; speedup vs baseline: 5.0019x; 1.3088x over previous
//
#include <hip/hip_runtime.h>
#include <cstddef>

// Shapes: B=8, CIN=128, N=2048, K=16, G=4, COUT=256, L=192, CL=48, NL=64, CNL=16
constexpr int NN = 2048;
constexpr int GG = 4;

// ---------------------------------------------------------------------------
// prep_q: Qbuf[g][c2][row] f32 (row<64: M_g[row][c2] = sum_o Wk[o][row]Wq[o][c2];
// row>=64: W2q_g[row-64][c2] = sum_o pe_w2[row-64][o]Wq[o][c2]), o in group g.
// ---------------------------------------------------------------------------
__global__ __launch_bounds__(256) void prep_q(const float* __restrict__ Wq,
                                              const float* __restrict__ Wk,
                                              const float* __restrict__ pe_w2,
                                              float* __restrict__ Qbuf) {
    const int g = blockIdx.x >> 6, c2 = blockIdx.x & 63;
    const int row = threadIdx.x;
    float acc = 0.f;
    if (row < 64) {
        for (int j = 0; j < 48; ++j) {
            const int o = g * 48 + j;
            acc = fmaf(Wk[o * 64 + row], Wq[o * 64 + c2], acc);
        }
    } else {
        const int d = row - 64;
        for (int j = 0; j < 48; ++j) {
            const int o = g * 48 + j;
            acc = fmaf(pe_w2[(size_t)d * 192 + o], Wq[o * 64 + c2], acc);
        }
    }
    Qbuf[((size_t)(g * 64 + c2) << 8) + row] = acc;
}

// ---------------------------------------------------------------------------
// local_v4: fused local branch, f32 logits, low-LDS (3 blocks/CU target).
// Block = (b, 8 n). x is read straight from global (L3-resident) twice.
// ---------------------------------------------------------------------------
__global__ __launch_bounds__(256, 3) void local_v4(
    const float* __restrict__ x, const float* __restrict__ abs_x,
    const float* __restrict__ points, const float* __restrict__ Wv,
    const float* __restrict__ pe_w1, const float* __restrict__ pe_b1,
    const int* __restrict__ idx, const float* __restrict__ Qbuf,
    float* __restrict__ out, float* __restrict__ cent)
{
    const int bn = blockIdx.x;
    const int b  = bn >> 8;
    const int n0 = (bn & 255) << 3;
    const int tid = threadIdx.x;

    __shared__ int   sidx[128];
    __shared__ float sa2[64][8];
    __shared__ float spts[3][8][16];
    __shared__ float sq[4][8][65];                  // q~ per (g,nl,c)
    __shared__ __align__(16) float s_union[4 * 8 * 193];  // sw then sxw
    __shared__ float spartA[128][9];                // logitA partials (slot h*4+g)
    __shared__ float spartB[128][9];                // h-contraction partials
    __shared__ float satt[4][128];

    float* sw  = s_union;                           // sw[(g*8+nl)*193 + d]
    float* sxw = s_union;                           // sxw[(g*128+c)*8 + nl]

    // ---- stage0: idx, a2 ----
    if (tid < 128) sidx[tid] = idx[((size_t)b * NN + n0) * 16 + tid];
    for (int i = tid; i < 512; i += 256) {
        int c = i >> 3, nl = i & 7;
        sa2[c][nl] = abs_x[((size_t)b * 64 + c) * NN + n0 + nl];
    }
    __syncthreads();

    // ---- spts gather + Q-stage: [q~; w~] = Qbuf_g @ a2 ----
    for (int i = tid; i < 384; i += 256) {
        int c = i >> 7, r = i & 127;
        spts[c][r >> 4][r & 15] = points[((size_t)b * 3 + c) * NN + sidx[r]];
    }
    for (int g = 0; g < 4; ++g) {
        const float* qb = Qbuf + ((size_t)g << 14) + tid;   // (g*64+c2)*256 + row
        float acc[8] = {0.f, 0.f, 0.f, 0.f, 0.f, 0.f, 0.f, 0.f};
        for (int c2 = 0; c2 < 64; ++c2) {
            const float qv = qb[c2 << 8];
            const float4 a0 = *(const float4*)&sa2[c2][0];
            const float4 a1 = *(const float4*)&sa2[c2][4];
            acc[0] = fmaf(qv, a0.x, acc[0]); acc[1] = fmaf(qv, a0.y, acc[1]);
            acc[2] = fmaf(qv, a0.z, acc[2]); acc[3] = fmaf(qv, a0.w, acc[3]);
            acc[4] = fmaf(qv, a1.x, acc[4]); acc[5] = fmaf(qv, a1.y, acc[5]);
            acc[6] = fmaf(qv, a1.z, acc[6]); acc[7] = fmaf(qv, a1.w, acc[7]);
        }
        if (tid < 64) {
            #pragma unroll
            for (int nl = 0; nl < 8; ++nl) sq[g][nl][tid] = acc[nl];
        } else {
            #pragma unroll
            for (int nl = 0; nl < 8; ++nl) sw[((g << 3) + nl) * 193 + (tid - 64)] = acc[nl];
        }
    }
    __syncthreads();

    // ---- logitA partials: spartA[col][ch*4+g] = sum_{c in half} q~[g][nl][c]*xsum ----
    {
        const int col = tid & 127, ch = tid >> 7;   // c range [ch*32, ch*32+32)
        const int nl = col >> 4, kk = col & 15;
        const float* xp = x + (((size_t)(b * 128 + ch * 32) * NN) + n0 + nl) * 16 + kk;
        const float* q0 = &sq[0][nl][ch * 32];
        const float* q1 = &sq[1][nl][ch * 32];
        const float* q2 = &sq[2][nl][ch * 32];
        const float* q3 = &sq[3][nl][ch * 32];
        float a0 = 0.f, a1 = 0.f, a2 = 0.f, a3 = 0.f;
        for (int i = 0; i < 32; ++i) {
            const float xs = xp[0] + xp[(size_t)64 * NN * 16];
            xp += NN * 16;
            a0 = fmaf(q0[i], xs, a0);
            a1 = fmaf(q1[i], xs, a1);
            a2 = fmaf(q2[i], xs, a2);
            a3 = fmaf(q3[i], xs, a3);
        }
        spartA[col][ch * 4 + 0] = a0; spartA[col][ch * 4 + 1] = a1;
        spartA[col][ch * 4 + 2] = a2; spartA[col][ch * 4 + 3] = a3;
    }
    // ---- h partials: spartB[col][dh*4+g] = sum_{d in half} relu(h)*w~[g][nl][d] ----
    {
        const int col = tid & 127, dh = tid >> 7;
        const int nl = col >> 4, kk = col & 15;
        const float r0 = spts[0][nl][kk] - spts[0][nl][0];
        const float r1 = spts[1][nl][kk] - spts[1][nl][0];
        const float r2 = spts[2][nl][kk] - spts[2][nl][0];
        float p0 = 0.f, p1 = 0.f, p2 = 0.f, p3 = 0.f;
        const int d0 = dh * 96;
        const float* w0 = &sw[((0 << 3) + nl) * 193];
        const float* w1 = &sw[((1 << 3) + nl) * 193];
        const float* w2 = &sw[((2 << 3) + nl) * 193];
        const float* w3 = &sw[((3 << 3) + nl) * 193];
        for (int d = d0; d < d0 + 96; ++d) {
            float h = fmaf(r0, pe_w1[d], fmaf(r1, pe_w1[192 + d], fmaf(r2, pe_w1[384 + d], pe_b1[d])));
            h = fmaxf(h, 0.f);
            p0 = fmaf(h, w0[d], p0);
            p1 = fmaf(h, w1[d], p1);
            p2 = fmaf(h, w2[d], p2);
            p3 = fmaf(h, w3[d], p3);
        }
        spartB[col][dh * 4 + 0] = p0; spartB[col][dh * 4 + 1] = p1;
        spartB[col][dh * 4 + 2] = p2; spartB[col][dh * 4 + 3] = p3;
    }
    __syncthreads();

    // ---- softmax over kk per (g,nl); scatter att into cent ----
    if (tid < 32) {
        const int g = tid >> 3, nl = tid & 7;
        float lg[16], m = -1e30f;
        #pragma unroll
        for (int kk = 0; kk < 16; ++kk) {
            const int col = nl * 16 + kk;
            lg[kk] = (spartA[col][g] + spartA[col][4 + g])
                   + (spartB[col][g] + spartB[col][4 + g]);
            m = fmaxf(m, lg[kk]);
        }
        float s = 0.f;
        #pragma unroll
        for (int kk = 0; kk < 16; ++kk) { lg[kk] = __expf(lg[kk] - m); s += lg[kk]; }
        const float inv = 1.f / s;
        #pragma unroll
        for (int kk = 0; kk < 16; ++kk) {
            const float a = lg[kk] * inv;
            satt[g][nl * 16 + kk] = a;
            atomicAdd(&cent[((size_t)(b * GG + g) << 11) + sidx[nl * 16 + kk]], a);
        }
    }
    __syncthreads();

    // ---- xw[g][c][nl] = sum_kk x[c][nl*16+kk]*att[g][...] (x from global, f32) ----
    #pragma unroll
    for (int t = 0; t < 4; ++t) {
        const int i2 = t * 256 + tid;
        const int c = i2 >> 3, nl = i2 & 7;
        const float* xp = x + (((size_t)(b * 128 + c) * NN) + n0 + nl) * 16;
        const float4 x0 = *(const float4*)(xp);
        const float4 x1 = *(const float4*)(xp + 4);
        const float4 x2 = *(const float4*)(xp + 8);
        const float4 x3 = *(const float4*)(xp + 12);
        const float xv[16] = {x0.x, x0.y, x0.z, x0.w, x1.x, x1.y, x1.z, x1.w,
                              x2.x, x2.y, x2.z, x2.w, x3.x, x3.y, x3.z, x3.w};
        #pragma unroll
        for (int g = 0; g < 4; ++g) {
            float v = 0.f;
            #pragma unroll
            for (int kk = 0; kk < 16; ++kk) v = fmaf(xv[kk], satt[g][nl * 16 + kk], v);
            sxw[((g << 7) + c) * 8 + nl] = v;
        }
    }
    __syncthreads();

    // ---- out[o][n] = Wv[o,:] . xw[g(o)][:,n] ----
    for (int i = tid; i < 1536; i += 256) {
        const int o = i >> 3, nl = i & 7;
        const int g = o / 48;
        const float* wv = Wv + (size_t)o * 128;
        const float* xwp = &sxw[(size_t)(g << 7) * 8 + nl];
        float a = 0.f;
        for (int c = 0; c < 128; c += 4) {
            const float4 w4 = *(const float4*)(wv + c);
            a = fmaf(w4.x, xwp[(c + 0) * 8], a);
            a = fmaf(w4.y, xwp[(c + 1) * 8], a);
            a = fmaf(w4.z, xwp[(c + 2) * 8], a);
            a = fmaf(w4.w, xwp[(c + 3) * 8], a);
        }
        out[(((size_t)b << 8) + o) * NN + n0 + nl] = a;
    }
}

// ---------------------------------------------------------------------------
// Kernel C: per (b,g): top-16 of cent row, then nonlocal prep (unchanged).
// ---------------------------------------------------------------------------
__global__ __launch_bounds__(256) void topk_prep_kernel(
    const float* __restrict__ abs_x, const float* __restrict__ points,
    const float* __restrict__ Wnk, const float* __restrict__ Wnv2,
    const float* __restrict__ npe_w1, const float* __restrict__ npe_b1,
    const float* __restrict__ npe_w2, const float* __restrict__ npe_b2,
    const float* __restrict__ cent,
    float* __restrict__ nkpe, float* __restrict__ nv2j, float* __restrict__ tanhv)
{
    const int bg  = blockIdx.x;
    const int b   = bg >> 2, g = bg & 3;
    const int tid = threadIdx.x;
    __shared__ float sc[2048];
    __shared__ float rv[4];  __shared__ int ri[4];
    __shared__ float svals[16]; __shared__ int sinds[16];
    __shared__ float srel[3][16];
    __shared__ float sh2[16][16];

    for (int i = tid; i < 2048; i += 256) sc[i] = cent[((size_t)bg << 11) + i];
    __syncthreads();
    for (int t = 0; t < 16; ++t) {
        float bv = -1e30f; int bi = 1 << 30;
        for (int i = tid; i < 2048; i += 256) {
            float v = sc[i];
            if (v > bv) { bv = v; bi = i; }
        }
        #pragma unroll
        for (int off = 1; off < 64; off <<= 1) {
            float ov = __shfl_xor(bv, off, 64);
            int   oi = __shfl_xor(bi, off, 64);
            if (ov > bv || (ov == bv && oi < bi)) { bv = ov; bi = oi; }
        }
        if ((tid & 63) == 0) { rv[tid >> 6] = bv; ri[tid >> 6] = bi; }
        __syncthreads();
        if (tid == 0) {
            for (int w = 1; w < 4; ++w)
                if (rv[w] > bv || (rv[w] == bv && ri[w] < bi)) { bv = rv[w]; bi = ri[w]; }
            svals[t] = bv; sinds[t] = bi;
            sc[bi] = -1e30f;
        }
        __syncthreads();
    }

    if (tid < 48) {
        int c = tid >> 4, j = tid & 15;
        srel[c][j] = points[((size_t)b * 3 + c) * NN + sinds[j]]
                   - points[((size_t)b * 3 + c) * NN + sinds[0]];
    }
    __syncthreads();
    {
        int j = tid >> 4, d = tid & 15;
        float a = npe_b1[g * 16 + d];
        #pragma unroll
        for (int c = 0; c < 3; ++c) a = fmaf(srel[c][j], npe_w1[((g * 3 + c) << 4) + d], a);
        sh2[j][d] = fmaxf(a, 0.f);
    }
    __syncthreads();
    {
        int c = tid >> 4, j = tid & 15;
        float a = npe_b2[g * 16 + c];
        #pragma unroll
        for (int d = 0; d < 16; ++d) a = fmaf(sh2[j][d], npe_w2[((g * 16 + d) << 4) + c], a);
        float nk = 0.f, nv = 0.f;
        const int col = sinds[j];
        const float* a2  = abs_x + (size_t)b * 64 * NN + col;
        const float* wkr = Wnk  + ((size_t)(g * 16 + c) << 6);
        const float* wvr = Wnv2 + ((size_t)(g * 16 + c) << 6);
        for (int ci = 0; ci < 64; ++ci) {
            float av = a2[(size_t)ci * NN];
            nk = fmaf(wkr[ci], av, nk);
            nv = fmaf(wvr[ci], av, nv);
        }
        nkpe[((size_t)bg << 8) + (c << 4) + j] = nk + a;
        nv2j[((size_t)bg << 8) + (c << 4) + j] = nv;
    }
    if (tid < 16) tanhv[(bg << 4) + tid] = tanhf(svals[tid]);
}

// ---------------------------------------------------------------------------
// Kernel D: nonlocal branch (unchanged).
// ---------------------------------------------------------------------------
__global__ __launch_bounds__(256) void nonlocal_kernel(
    const float* __restrict__ abs_x,
    const float* __restrict__ Wnq, const float* __restrict__ Wnv1, const float* __restrict__ Wnv2,
    const float* __restrict__ nkpe, const float* __restrict__ nv2j, const float* __restrict__ tanhv,
    float* __restrict__ out)
{
    const int blk = blockIdx.x;
    const int b   = blk >> 5;
    const int n0  = (blk & 31) << 6;
    const int tid = threadIdx.x;
    const int nl  = tid & 63;
    const int g   = tid >> 6;

    __shared__ float sa2[64][64];
    __shared__ float snkpe[4][16][16];
    __shared__ float snv2j[4][16][16];
    __shared__ float stanh[4][16];

    for (int i = tid; i < 64 * 64; i += 256) {
        int ci = i >> 6, c2 = i & 63;
        sa2[ci][c2] = abs_x[((size_t)b * 64 + ci) * NN + n0 + c2];
    }
    for (int i = tid; i < 1024; i += 256) {
        ((float*)snkpe)[i] = nkpe[((size_t)b << 10) + i];
        ((float*)snv2j)[i] = nv2j[((size_t)b << 10) + i];
    }
    if (tid < 64) ((float*)stanh)[tid] = tanhv[(b << 6) + tid];
    __syncthreads();

    float nq[16], nv1[16], nv2[16];
    #pragma unroll
    for (int c = 0; c < 16; ++c) { nq[c] = 0.f; nv1[c] = 0.f; nv2[c] = 0.f; }
    const float* wq  = Wnq  + (size_t)(g << 4) * 64;
    const float* wv1 = Wnv1 + (size_t)(g << 4) * 64;
    const float* wv2 = Wnv2 + (size_t)(g << 4) * 64;
    for (int ci = 0; ci < 64; ++ci) {
        const float a = sa2[ci][nl];
        #pragma unroll
        for (int c = 0; c < 16; ++c) {
            nq[c]  = fmaf(wq [(c << 6) + ci], a, nq[c]);
            nv1[c] = fmaf(wv1[(c << 6) + ci], a, nv1[c]);
            nv2[c] = fmaf(wv2[(c << 6) + ci], a, nv2[c]);
        }
    }

    float lg[16];
    #pragma unroll
    for (int j = 0; j < 16; ++j) {
        float a = 0.f;
        #pragma unroll
        for (int c = 0; c < 16; ++c) a = fmaf(nq[c], snkpe[g][c][j], a);
        lg[j] = a;
    }
    float m = lg[0];
    #pragma unroll
    for (int j = 1; j < 16; ++j) m = fmaxf(m, lg[j]);
    float s = 0.f;
    float w[16];
    #pragma unroll
    for (int j = 0; j < 16; ++j) { w[j] = __expf(lg[j] - m); s += w[j]; }
    const float inv = 1.f / s;
    float ws = 0.f;
    #pragma unroll
    for (int j = 0; j < 16; ++j) { w[j] = w[j] * inv * stanh[g][j]; ws += w[j]; }
    #pragma unroll
    for (int c = 0; c < 16; ++c) {
        float v = (nv1[c] - nv2[c]) * ws;
        #pragma unroll
        for (int j = 0; j < 16; ++j) v = fmaf(w[j], snv2j[g][c][j], v);
        out[(((size_t)b << 8) + 192 + (g << 4) + c) * NN + n0 + nl] = v;
    }
}

// ---------------------------------------------------------------------------
extern "C" void kernel_launch(void* const* d_in, const int* in_sizes, int n_in,
                              void* d_out, int out_size, void* d_ws, size_t ws_size,
                              hipStream_t stream)
{
    (void)in_sizes; (void)n_in; (void)out_size; (void)ws_size;
    const float* x      = (const float*)d_in[0];
    const float* abs_x  = (const float*)d_in[1];
    const float* points = (const float*)d_in[2];
    const float* Wq     = (const float*)d_in[3];
    const float* Wk     = (const float*)d_in[4];
    const float* Wv     = (const float*)d_in[5];
    const float* Wnq    = (const float*)d_in[6];
    const float* Wnk    = (const float*)d_in[7];
    const float* Wnv1   = (const float*)d_in[8];
    const float* Wnv2   = (const float*)d_in[9];
    const float* pe_w1  = (const float*)d_in[10];
    const float* pe_b1  = (const float*)d_in[11];
    const float* pe_w2  = (const float*)d_in[12];
    // pe_b2 (d_in[13]): constant logit shift per (g,n) -> cancels in softmax
    const float* npe_w1 = (const float*)d_in[14];
    const float* npe_b1 = (const float*)d_in[15];
    const float* npe_w2 = (const float*)d_in[16];
    const float* npe_b2 = (const float*)d_in[17];
    const int*   idx    = (const int*)d_in[18];
    float* out = (float*)d_out;

    // ws layout (floats): cent[65536] | Qbuf[65536] | nkpe[8192] | nv2j[8192] | tanh[512]
    float* cent  = (float*)d_ws;
    float* Qbuf  = cent + 65536;
    float* nkpeW = Qbuf + 65536;
    float* nv2jW = nkpeW + 8192;
    float* tanhW = nv2jW + 8192;

    hipMemsetAsync(cent, 0, (size_t)65536 * sizeof(float), stream);
    prep_q<<<256, 256, 0, stream>>>(Wq, Wk, pe_w2, Qbuf);
    local_v4<<<2048, 256, 0, stream>>>(x, abs_x, points, Wv, pe_w1, pe_b1,
                                       idx, Qbuf, out, cent);
    topk_prep_kernel<<<32, 256, 0, stream>>>(abs_x, points, Wnk, Wnv2,
                                             npe_w1, npe_b1, npe_w2, npe_b2,
                                             cent, nkpeW, nv2jW, tanhW);
    nonlocal_kernel<<<8 * 32, 256, 0, stream>>>(abs_x, Wnq, Wnv1, Wnv2,
                                                nkpeW, nv2jW, tanhW, out);
}